// Round 11
// baseline (124.754 us; speedup 1.0000x reference)
//
#include <hip/hip_runtime.h>
#include <math.h>

// Problem constants: L=5, B=8, n=1024, d=64
#define LL 5
#define BB 8
#define NN 1024
#define DD 64
#define LB 40              // (l,b) pairs
#define SPLIT 16           // n-split: gram blocks per (l,b)
#define KC (NN / SPLIT)    // 64 k-rows per gram block
#define ZC (2 * DD)        // Z = [X | Y], 128 columns
#define NQ 3               // stored quadrants: 0=XX, 1=XY, 2=YY (YX dup skipped)

// Workspace layout (floats unless noted)
// Gp: bf16 partial quadrants (row-pair packed): LB*SPLIT*NQ*4096 shorts = 15.7 MB
#define GP_SHORTS (LB * SPLIT * NQ * 4096)
#define GP_FLOATS (GP_SHORTS / 2)
#define SP_OFF GP_FLOATS                   // Sp: LB*SPLIT*ZC floats
#define ACC_OFF (SP_OFF + LB * SPLIT * ZC) // Acc: LB*4 floats {vxx,hxy,vyy,pad}
#define CNT_OFF (ACC_OFF + LB * 4)         // counters: LB per-lb + 1 final (uints)

typedef short short8 __attribute__((ext_vector_type(8)));   // 8 bf16 = 4 VGPRs
typedef float floatx4 __attribute__((ext_vector_type(4)));  // MFMA C/D

__device__ __forceinline__ unsigned short f2bf(float f) {
    union { float f; unsigned u; } v; v.f = f;
    const unsigned u = v.u;
    return (unsigned short)((u + 0x7FFFu + ((u >> 16) & 1u)) >> 16);  // RNE
}
__device__ __forceinline__ float bf2f(unsigned short h) {
    union { unsigned u; float f; } v; v.u = ((unsigned)h) << 16; return v.f;
}
__device__ __forceinline__ float bflo(unsigned u) {
    union { unsigned u; float f; } v; v.u = u << 16; return v.f;
}
__device__ __forceinline__ float bfhi(unsigned u) {
    union { unsigned u; float f; } v; v.u = u & 0xFFFF0000u; return v.f;
}

// LDS: bf16 K-major per Z-column, KC=64 (8 octets/col).
// Element (c,k) at short-index: c*64 + ((((k>>3) ^ ((c+(c>>4)) & 15)) & 7) << 3) + (k&7).
// Conflict-free for both b128 staging writes and b128 frag reads (R7/R8-verified).
__device__ __forceinline__ short8 read_frag(const short* Zt, int tbase, int lane, int k0) {
    const int c = tbase + (lane & 15);
    const int o = (k0 >> 3) + (lane >> 4);
    const int oct = (o ^ ((c + (c >> 4)) & 15)) & 7;
    return *(const short8*)(Zt + c * 64 + (oct << 3));
}

// Single ordinary kernel, grid = 640 x 256. Phase 1: per-block partial gram
// (R8 body). Election A (per-lb counter): last of an lb's 16 blocks reduces
// that lb (center + Frobenius) and stores {vxx,hxy,vyy}. Election B (global
// counter): last of the 40 reducers computes the loss. No waiting anywhere ->
// no co-residency requirement.
__global__ __launch_bounds__(256) void cka_all(const float* __restrict__ X,
                                               const float* __restrict__ Y,
                                               unsigned* __restrict__ Gp,
                                               float* __restrict__ Sp,
                                               float* __restrict__ Acc,
                                               unsigned* __restrict__ cnt,
                                               float* __restrict__ out) {
    __shared__ short Zt[ZC * KC];      // 16 KB (phase 1)
    __shared__ float cscr[8][ZC];      // 4 KB  (phase 1)
    __shared__ float stot[ZC];         // reduce
    __shared__ float redq[NQ][4];      // reduce
    __shared__ int elect;

    const int bid = blockIdx.x;
    const int tid = threadIdx.x;
    const int lb = bid / SPLIT, nc = bid % SPLIT;

    // ================= Phase 1: partial gram (R8 body, runtime-proven) ======
    {
        const int r0 = nc * KC;
        const float4* X4 = (const float4*)(X + (size_t)lb * NN * DD);
        const float4* Y4 = (const float4*)(Y + (size_t)lb * NN * DD);

        const int col4 = tid & 31;
        const int rb = tid >> 5;
        float4 v[8];
#pragma unroll
        for (int m = 0; m < 8; ++m) {
            const int row = 8 * rb + m;
            v[m] = (col4 < 16) ? X4[(size_t)(r0 + row) * 16 + col4]
                               : Y4[(size_t)(r0 + row) * 16 + (col4 - 16)];
        }

#pragma unroll
        for (int e = 0; e < 4; ++e) {
            const int c = 4 * col4 + e;
            short8 w8;
            float cs = 0.f;
#pragma unroll
            for (int m = 0; m < 8; ++m) {
                const float fv = (e == 0) ? v[m].x : (e == 1) ? v[m].y
                               : (e == 2) ? v[m].z : v[m].w;
                const unsigned short b = f2bf(fv);
                cs += bf2f(b);
                w8[m] = (short)b;
            }
            const int oct = (rb ^ ((c + (c >> 4)) & 15)) & 7;
            *(short8*)(Zt + c * 64 + (oct << 3)) = w8;
            cscr[rb][c] = cs;
        }
        __syncthreads();
        if (tid < ZC) {
            float s = 0.f;
#pragma unroll
            for (int g = 0; g < 8; ++g) s += cscr[g][tid];
            Sp[(lb * SPLIT + nc) * ZC + tid] = s;
        }

        const int lane = tid & 63, w = tid >> 6;
        const int jbeg = (w < 2) ? 0 : 4;   // upper waves skip YX col-tiles

        floatx4 acc[2][8];
#pragma unroll
        for (int i = 0; i < 2; ++i)
#pragma unroll
            for (int j = 0; j < 8; ++j) acc[i][j] = (floatx4){0.f, 0.f, 0.f, 0.f};

#pragma unroll
        for (int k0 = 0; k0 < KC; k0 += 32) {
            short8 af[2], bfr[8];
#pragma unroll
            for (int i = 0; i < 2; ++i) af[i] = read_frag(Zt, (2 * w + i) * 16, lane, k0);
#pragma unroll
            for (int j = 0; j < 8; ++j)
                if (j >= jbeg) bfr[j] = read_frag(Zt, j * 16, lane, k0);
#pragma unroll
            for (int i = 0; i < 2; ++i)
#pragma unroll
                for (int j = 0; j < 8; ++j)
                    if (j >= jbeg)
                        acc[i][j] = __builtin_amdgcn_mfma_f32_16x16x32_bf16(af[i], bfr[j], acc[i][j], 0, 0, 0);
        }

        // bf16 row-pair-packed stores; C/D: col = lane&15, row = (lane>>4)*4 + r
        unsigned* Gb = Gp + (size_t)(lb * SPLIT + nc) * (NQ * 2048);
        const int g = lane >> 4, cl = lane & 15;
#pragma unroll
        for (int i = 0; i < 2; ++i)
#pragma unroll
            for (int j = 0; j < 8; ++j) {
                if (j < jbeg) continue;
                const int slab = (w < 2) ? ((j < 4) ? 0 : 1) : 2;
                const int qrow0 = (w < 2 ? (2 * w + i) : (2 * (w - 2) + i)) * 16 + g * 4;
                const int qcol = (j & 3) * 16 + cl;
                const unsigned lo = (unsigned)f2bf(acc[i][j][0]) | ((unsigned)f2bf(acc[i][j][1]) << 16);
                const unsigned hi = (unsigned)f2bf(acc[i][j][2]) | ((unsigned)f2bf(acc[i][j][3]) << 16);
                Gb[slab * 2048 + (qrow0 >> 1) * 64 + qcol] = lo;
                Gb[slab * 2048 + ((qrow0 >> 1) + 1) * 64 + qcol] = hi;
            }
    }

    // ================= Election A: last block of this lb reduces it =========
    __syncthreads();                       // all waves drained their stores
    if (tid == 0) {
        __threadfence();                   // release: partials visible device-wide
        const unsigned old = atomicAdd(&cnt[lb], 1u);
        elect = (old == SPLIT - 1);
    }
    __syncthreads();
    if (!elect) return;
    __threadfence();                       // acquire

    // ---- reduce this lb: sum 16 bf16 partials, center, Frobenius ----
    if (tid < ZC) {
        float s = 0.f;
#pragma unroll
        for (int sp = 0; sp < SPLIT; ++sp) s += Sp[(lb * SPLIT + sp) * ZC + tid];
        stot[tid] = s;
    }
    __syncthreads();

    const float inv_n = 1.0f / (float)NN;
    float sqq[NQ] = {0.f, 0.f, 0.f};
#pragma unroll
    for (int q = 0; q < NQ; ++q) {
        const int rowbase = (q == 2) ? 64 : 0;
        const int colbase = (q == 0) ? 0 : 64;
#pragma unroll
        for (int j = 0; j < 2; ++j) {
            const int u0 = tid * 8 + j * 4;        // uint idx within quadrant
            const int rp = u0 >> 6, c0 = u0 & 63;  // row-pair, columns c0..c0+3
            float g[8] = {0.f, 0.f, 0.f, 0.f, 0.f, 0.f, 0.f, 0.f};
#pragma unroll
            for (int sp = 0; sp < SPLIT; ++sp) {
                const uint4 p = *(const uint4*)&Gp[((size_t)(lb * SPLIT + sp) * NQ + q) * 2048 + u0];
                g[0] += bflo(p.x); g[1] += bfhi(p.x);
                g[2] += bflo(p.y); g[3] += bfhi(p.y);
                g[4] += bflo(p.z); g[5] += bfhi(p.z);
                g[6] += bflo(p.w); g[7] += bfhi(p.w);
            }
            const float sr0 = stot[rowbase + 2 * rp] * inv_n;
            const float sr1 = stot[rowbase + 2 * rp + 1] * inv_n;
#pragma unroll
            for (int e = 0; e < 4; ++e) {
                const float sc = stot[colbase + c0 + e];
                const float cv0 = g[2 * e] - sr0 * sc;
                const float cv1 = g[2 * e + 1] - sr1 * sc;
                sqq[q] += cv0 * cv0 + cv1 * cv1;
            }
        }
    }
#pragma unroll
    for (int off = 32; off; off >>= 1) {
        sqq[0] += __shfl_down(sqq[0], off);
        sqq[1] += __shfl_down(sqq[1], off);
        sqq[2] += __shfl_down(sqq[2], off);
    }
    const int wave = tid >> 6;
    if ((tid & 63) == 0) { redq[0][wave] = sqq[0]; redq[1][wave] = sqq[1]; redq[2][wave] = sqq[2]; }
    __syncthreads();

    // ================= Election B: last reducer computes the loss ===========
    if (tid == 0) {
#pragma unroll
        for (int q = 0; q < NQ; ++q)
            Acc[lb * 4 + q] = redq[q][0] + redq[q][1] + redq[q][2] + redq[q][3];
        __threadfence();                   // release Acc
        const unsigned old2 = atomicAdd(&cnt[LB], 1u);
        elect = (old2 == LB - 1);
    }
    __syncthreads();
    if (!elect) return;
    __threadfence();                       // acquire all Acc

    if (tid < 64) {
        float v = 0.0f;
        if (tid < LB) {
            const float vxx = Acc[tid * 4 + 0];
            const float hxy = Acc[tid * 4 + 1];
            const float vyy = Acc[tid * 4 + 2];
            v = fabsf(hxy / (sqrtf(vxx) * sqrtf(vyy)));
        }
        v += __shfl_xor(v, 1);
        v += __shfl_xor(v, 2);
        v += __shfl_xor(v, 4);
        float loss = 0.0f;
#pragma unroll
        for (int l = 0; l < LL; ++l) {
            const float sl = __shfl(v, l * BB);
            loss += -logf(sl * (1.0f / (float)BB) + 1e-8f);
        }
        if (tid == 0) out[0] = loss * (1.0f / (float)LL);
    }
}

extern "C" void kernel_launch(void* const* d_in, const int* in_sizes, int n_in,
                              void* d_out, int out_size, void* d_ws, size_t ws_size,
                              hipStream_t stream) {
    const float* teacher = (const float*)d_in[0];
    const float* student = (const float*)d_in[1];
    float* ws = (float*)d_ws;
    unsigned* Gp = (unsigned*)ws;
    float* Sp = ws + SP_OFF;
    float* Acc = ws + ACC_OFF;
    unsigned* cnt = (unsigned*)(ws + CNT_OFF);
    float* out = (float*)d_out;

    // Counters are poisoned 0xAA each call — zero them (tiny, capture-safe)
    hipMemsetAsync(cnt, 0, 64 * sizeof(unsigned), stream);
    cka_all<<<LB * SPLIT, 256, 0, stream>>>(teacher, student, Gp, Sp, Acc, cnt, out);
}

// Round 12
// 75.906 us; speedup vs baseline: 1.6435x; 1.6435x over previous
//
#include <hip/hip_runtime.h>
#include <math.h>

// Problem constants: L=5, B=8, n=1024, d=64
#define LL 5
#define BB 8
#define NN 1024
#define DD 64
#define LB 40              // (l,b) pairs
#define SPLIT 16           // n-split: blocks per (l,b)
#define KC (NN / SPLIT)    // 64 k-rows per block
#define ZC (2 * DD)        // Z = [X | Y], 128 columns
#define NQ 3               // stored quadrants: 0=XX, 1=XY, 2=YY (YX dup skipped)

// Workspace layout
// Gp: bf16 partial quadrants, LB*SPLIT*NQ*4096 shorts = 15.7 MB
// Quadrant element (row,col) -> short index (row>>1)*128 + col*2 + (row&1)
#define GP_SHORTS (LB * SPLIT * NQ * 4096)
#define GP_FLOATS (GP_SHORTS / 2)
#define SP_OFF GP_FLOATS                   // Sp: LB*SPLIT*ZC floats
#define ACC_OFF (GP_FLOATS + LB * SPLIT * ZC)  // Acc2: LB x 3 x 4 segment sums

typedef short short8 __attribute__((ext_vector_type(8)));   // 8 bf16 = 4 VGPRs
typedef float floatx4 __attribute__((ext_vector_type(4)));  // MFMA C/D

__device__ __forceinline__ unsigned short f2bf(float f) {
    union { float f; unsigned u; } v; v.f = f;
    const unsigned u = v.u;
    return (unsigned short)((u + 0x7FFFu + ((u >> 16) & 1u)) >> 16);  // RNE
}
__device__ __forceinline__ float bf2f(unsigned short h) {
    union { unsigned u; float f; } v; v.u = ((unsigned)h) << 16; return v.f;
}
__device__ __forceinline__ float bflo(unsigned u) {
    union { unsigned u; float f; } v; v.u = u << 16; return v.f;
}
__device__ __forceinline__ float bfhi(unsigned u) {
    union { unsigned u; float f; } v; v.u = u & 0xFFFF0000u; return v.f;
}

// LDS: bf16 K-major per Z-column, KC=64 (8 octets/col).
// Element (c,k) at short-index: c*64 + ((((k>>3) ^ ((c+(c>>4)) & 15)) & 7) << 3) + (k&7).
// Conflict-free for both b128 staging writes and b128 frag reads (R7-verified).
__device__ __forceinline__ short8 read_frag(const short* Zt, int tbase, int lane, int k0) {
    const int c = tbase + (lane & 15);
    const int o = (k0 >> 3) + (lane >> 4);
    const int oct = (o ^ ((c + (c >> 4)) & 15)) & 7;
    return *(const short8*)(Zt + c * 64 + (oct << 3));
}

// Kernel 1: per-block partial gram of a 64-row slice of Z via MFMA.
// grid (SPLIT, LB) x 256 thr (4 waves). Waves 0,1: X row-tiles x all 8 col-tiles
// (XX + XY). Waves 2,3: Y row-tiles x Y col-tiles only (YY) — YX never computed.
// Partials stored bf16, row-pair packed.
__global__ __launch_bounds__(256) void gram_kernel(const float* __restrict__ X,
                                                   const float* __restrict__ Y,
                                                   unsigned* __restrict__ Gp,
                                                   float* __restrict__ Sp) {
    __shared__ short Zt[ZC * KC];      // 16 KB
    __shared__ float cscr[8][ZC];      // 4 KB col-sum scratch

    const int lb = blockIdx.y, nc = blockIdx.x, tid = threadIdx.x;
    const int r0 = nc * KC;
    const float4* X4 = (const float4*)(X + (size_t)lb * NN * DD);
    const float4* Y4 = (const float4*)(Y + (size_t)lb * NN * DD);

    // ---- load: 8 coalesced float4/thread; thread owns one k-octet ----
    const int col4 = tid & 31;
    const int rb = tid >> 5;
    float4 v[8];
#pragma unroll
    for (int m = 0; m < 8; ++m) {
        const int row = 8 * rb + m;
        v[m] = (col4 < 16) ? X4[(size_t)(r0 + row) * 16 + col4]
                           : Y4[(size_t)(r0 + row) * 16 + (col4 - 16)];
    }

    // ---- convert + pack + 4 x b128 LDS writes + bf16-consistent col sums ----
#pragma unroll
    for (int e = 0; e < 4; ++e) {
        const int c = 4 * col4 + e;
        short8 w8;
        float cs = 0.f;
#pragma unroll
        for (int m = 0; m < 8; ++m) {
            const float fv = (e == 0) ? v[m].x : (e == 1) ? v[m].y : (e == 2) ? v[m].z : v[m].w;
            const unsigned short b = f2bf(fv);
            cs += bf2f(b);
            w8[m] = (short)b;
        }
        const int oct = (rb ^ ((c + (c >> 4)) & 15)) & 7;
        *(short8*)(Zt + c * 64 + (oct << 3)) = w8;
        cscr[rb][c] = cs;
    }
    __syncthreads();
    if (tid < ZC) {
        float s = 0.f;
#pragma unroll
        for (int g = 0; g < 8; ++g) s += cscr[g][tid];
        Sp[(lb * SPLIT + nc) * ZC + tid] = s;
    }

    // ---- MFMA ----
    const int lane = tid & 63, w = tid >> 6;
    const int jbeg = (w < 2) ? 0 : 4;     // upper waves skip YX col-tiles

    floatx4 acc[2][8];
#pragma unroll
    for (int i = 0; i < 2; ++i)
#pragma unroll
        for (int j = 0; j < 8; ++j) acc[i][j] = (floatx4){0.f, 0.f, 0.f, 0.f};

#pragma unroll
    for (int k0 = 0; k0 < KC; k0 += 32) {
        short8 af[2], bfr[8];
#pragma unroll
        for (int i = 0; i < 2; ++i) af[i] = read_frag(Zt, (2 * w + i) * 16, lane, k0);
#pragma unroll
        for (int j = 0; j < 8; ++j)
            if (j >= jbeg) bfr[j] = read_frag(Zt, j * 16, lane, k0);
#pragma unroll
        for (int i = 0; i < 2; ++i)
#pragma unroll
            for (int j = 0; j < 8; ++j)
                if (j >= jbeg)
                    acc[i][j] = __builtin_amdgcn_mfma_f32_16x16x32_bf16(af[i], bfr[j], acc[i][j], 0, 0, 0);
    }

    // ---- store bf16 row-pair-packed partial quadrants ----
    // C/D: col = lane&15, row = (lane>>4)*4 + r. Rows g*4+{0,1}, g*4+{2,3} pack.
    unsigned* Gb = Gp + (size_t)(lb * SPLIT + nc) * (NQ * 2048);
    const int g = lane >> 4, cl = lane & 15;
#pragma unroll
    for (int i = 0; i < 2; ++i)
#pragma unroll
        for (int j = 0; j < 8; ++j) {
            if (j < jbeg) continue;
            const int slab = (w < 2) ? ((j < 4) ? 0 : 1) : 2;
            const int qrow0 = (w < 2 ? (2 * w + i) : (2 * (w - 2) + i)) * 16 + g * 4;
            const int qcol = (j & 3) * 16 + cl;
            const unsigned lo = (unsigned)f2bf(acc[i][j][0]) | ((unsigned)f2bf(acc[i][j][1]) << 16);
            const unsigned hi = (unsigned)f2bf(acc[i][j][2]) | ((unsigned)f2bf(acc[i][j][3]) << 16);
            Gb[slab * 2048 + (qrow0 >> 1) * 64 + qcol] = lo;
            Gb[slab * 2048 + ((qrow0 >> 1) + 1) * 64 + qcol] = hi;
        }
}

// Kernel 2: sum SPLIT bf16 partials, center (Gc = G - s s^T/n), Frobenius-reduce.
// grid = LB*NQ*4 = 480 blocks x 256 thr. Thread handles one uint2 = 2 cols x 2 rows
// per partial. Plain store per block into its own Acc2 slot (no atomics).
__global__ __launch_bounds__(256) void reduce_kernel(const unsigned* __restrict__ Gp,
                                                     const float* __restrict__ Sp,
                                                     float* __restrict__ Acc2) {
    const int b = blockIdx.x;
    const int lb = b / (NQ * 4);
    const int rem = b % (NQ * 4);
    const int q = rem >> 2, seg = rem & 3;
    const int tid = threadIdx.x;

    __shared__ float stot[ZC];
    __shared__ float red[4];

    if (tid < ZC) {
        float s = 0.f;
#pragma unroll
        for (int sp = 0; sp < SPLIT; ++sp) s += Sp[(lb * SPLIT + sp) * ZC + tid];
        stot[tid] = s;
    }
    __syncthreads();

    const int u0 = seg * 512 + tid * 2;      // uint index within 2048-uint quadrant
    const int rp = u0 >> 6;                  // row-pair
    const int c0 = u0 & 63;                  // column (c0, c0+1)

    float g00 = 0.f, g10 = 0.f, g01 = 0.f, g11 = 0.f;   // [row&1][col-e]
#pragma unroll
    for (int sp = 0; sp < SPLIT; ++sp) {
        const uint2 p = *(const uint2*)&Gp[((size_t)(lb * SPLIT + sp) * NQ + q) * 2048 + u0];
        g00 += bflo(p.x); g10 += bfhi(p.x);
        g01 += bflo(p.y); g11 += bfhi(p.y);
    }
    const int rowbase = (q == 2) ? 64 : 0;
    const int colbase = (q == 0) ? 0 : 64;
    const float inv_n = 1.0f / (float)NN;
    const float sr0 = stot[rowbase + 2 * rp] * inv_n;
    const float sr1 = stot[rowbase + 2 * rp + 1] * inv_n;
    const float sc0 = stot[colbase + c0];
    const float sc1 = stot[colbase + c0 + 1];
    float sq = 0.f;
    { const float cv = g00 - sr0 * sc0; sq += cv * cv; }
    { const float cv = g10 - sr1 * sc0; sq += cv * cv; }
    { const float cv = g01 - sr0 * sc1; sq += cv * cv; }
    { const float cv = g11 - sr1 * sc1; sq += cv * cv; }

#pragma unroll
    for (int off = 32; off; off >>= 1) sq += __shfl_down(sq, off);
    const int wave = tid >> 6;
    if ((tid & 63) == 0) red[wave] = sq;
    __syncthreads();
    if (tid == 0)
        Acc2[lb * 12 + q * 4 + seg] = red[0] + red[1] + red[2] + red[3];
}

// Kernel 3: sum segments, ratio, loss = mean_l(-log(mean_b(ratio)+eps))
__global__ void final_kernel(const float* __restrict__ Acc2, float* __restrict__ out) {
    const int tid = threadIdx.x;   // one wave
    float v = 0.0f;
    if (tid < LB) {
        float vxx = 0.f, hxy = 0.f, vyy = 0.f;
#pragma unroll
        for (int s = 0; s < 4; ++s) {
            vxx += Acc2[tid * 12 + s];
            hxy += Acc2[tid * 12 + 4 + s];
            vyy += Acc2[tid * 12 + 8 + s];
        }
        v = fabsf(hxy / (sqrtf(vxx) * sqrtf(vyy)));
    }
    v += __shfl_xor(v, 1);
    v += __shfl_xor(v, 2);
    v += __shfl_xor(v, 4);
    float loss = 0.0f;
#pragma unroll
    for (int l = 0; l < LL; ++l) {
        const float sl = __shfl(v, l * BB);
        loss += -logf(sl * (1.0f / (float)BB) + 1e-8f);
    }
    if (tid == 0) out[0] = loss * (1.0f / (float)LL);
}

extern "C" void kernel_launch(void* const* d_in, const int* in_sizes, int n_in,
                              void* d_out, int out_size, void* d_ws, size_t ws_size,
                              hipStream_t stream) {
    const float* teacher = (const float*)d_in[0];
    const float* student = (const float*)d_in[1];
    float* ws = (float*)d_ws;
    unsigned* Gp = (unsigned*)ws;
    float* Sp = ws + SP_OFF;
    float* Acc2 = ws + ACC_OFF;

    dim3 grid1(SPLIT, LB);
    gram_kernel<<<grid1, 256, 0, stream>>>(teacher, student, Gp, Sp);
    reduce_kernel<<<LB * NQ * 4, 256, 0, stream>>>(Gp, Sp, Acc2);
    final_kernel<<<1, 64, 0, stream>>>(Acc2, (float*)d_out);
}